// Round 1
// baseline (29.463 us; speedup 1.0000x reference)
//
#include <hip/hip_runtime.h>
#include <math.h>

// GaussianVisibility: R rays x B=24 bones x G=4 gaussians -> shadow map (R,)
// Memory-bound: w2ls (R,24,4,4) fp32 = 100.7 MB dominates. Target ~16us HBM roofline.
//
// Layout: 4 lanes per ray. lane sub loads w2ls row `sub` (float4, 16B) ->
// each wave load instruction covers 16 fully-consumed 64B cache lines.
// lane sub also owns gaussian g=sub. o/n vector components shared across the
// quad via DPP quad_perm broadcasts (VALU-only, no LDS pipe traffic).
// Per-(b,g) params (symmetric Sn1, mu, c) are ray-independent: computed once
// per block into LDS by the first 96 threads.

#define NB 24
#define NG 4
#define BASE_SCALE 0.001f

template <int CTRL>
__device__ __forceinline__ float dpp_f(float x) {
    int r = __builtin_amdgcn_update_dpp(0, __float_as_int(x), CTRL, 0xF, 0xF, true);
    return __int_as_float(r);
}

__device__ __forceinline__ float frcp(float x) { return __builtin_amdgcn_rcpf(x); }

__global__ __launch_bounds__(256) void gauss_vis_kernel(
    const float* __restrict__ w2ls,
    const float* __restrict__ rays_o,
    const float* __restrict__ rays_d,
    const float* __restrict__ Gs,
    float* __restrict__ out,
    int R)
{
    __shared__ float4 P[NB * NG * 3];  // per (b,g): {s00,s01,s02,s11},{s12,s22,mu0,mu1},{mu2,c,-,-}

    const int tid = threadIdx.x;

    // ---- per-block param precompute (ray-independent) ----
    if (tid < NB * NG) {
        const float* gp = Gs + tid * 13;
        float mu0 = gp[0], mu1 = gp[1], mu2 = gp[2];
        float s0 = fabsf(gp[3]) + BASE_SCALE;
        float s1 = fabsf(gp[4]) + BASE_SCALE;
        float s2 = fabsf(gp[5]) + BASE_SCALE;
        float ax = gp[6], ay = gp[7], az = gp[8];
        float bx = gp[9], by = gp[10], bz = gp[11];
        float c = fabsf(gp[12]);
        // rot6d -> orthonormal basis (b1,b2,b3 are the matrix COLUMNS)
        float inv1 = 1.0f / sqrtf(ax * ax + ay * ay + az * az);
        float b1x = ax * inv1, b1y = ay * inv1, b1z = az * inv1;
        float dot = b1x * bx + b1y * by + b1z * bz;
        float t2x = bx - dot * b1x, t2y = by - dot * b1y, t2z = bz - dot * b1z;
        float inv2 = 1.0f / sqrtf(t2x * t2x + t2y * t2y + t2z * t2z);
        float b2x = t2x * inv2, b2y = t2y * inv2, b2z = t2z * inv2;
        float b3x = b1y * b2z - b1z * b2y;
        float b3y = b1z * b2x - b1x * b2z;
        float b3z = b1x * b2y - b1y * b2x;
        // Sn1[i][j] = sum_k basis_i[k] * basis_j[k] / std[k]^2  (symmetric)
        float w0 = 1.0f / (s0 * s0), w1 = 1.0f / (s1 * s1), w2 = 1.0f / (s2 * s2);
        float s00 = b1x * b1x * w0 + b1y * b1y * w1 + b1z * b1z * w2;
        float s01 = b1x * b2x * w0 + b1y * b2y * w1 + b1z * b2z * w2;
        float s02 = b1x * b3x * w0 + b1y * b3y * w1 + b1z * b3z * w2;
        float s11 = b2x * b2x * w0 + b2y * b2y * w1 + b2z * b2z * w2;
        float s12 = b2x * b3x * w0 + b2y * b3y * w1 + b2z * b3z * w2;
        float s22 = b3x * b3x * w0 + b3y * b3y * w1 + b3z * b3z * w2;
        P[tid * 3 + 0] = make_float4(s00, s01, s02, s11);
        P[tid * 3 + 1] = make_float4(s12, s22, mu0, mu1);
        P[tid * 3 + 2] = make_float4(mu2, c, 0.f, 0.f);
    }
    __syncthreads();

    const int gid = blockIdx.x * 256 + tid;
    const int ray = gid >> 2;
    const int sub = tid & 3;
    if (ray >= R) return;  // quads stay intact (4 lanes/ray)

    const float rox = rays_o[ray * 3 + 0];
    const float roy = rays_o[ray * 3 + 1];
    const float roz = rays_o[ray * 3 + 2];
    const float rdx = rays_d[ray * 3 + 0];
    const float rdy = rays_d[ray * 3 + 1];
    const float rdz = rays_d[ray * 3 + 2];

    const float4* __restrict__ Wv = (const float4*)w2ls;
    const size_t wbase = (size_t)ray * (NB * 4) + sub;

    float sum = 0.f;
#pragma unroll 4
    for (int b = 0; b < NB; ++b) {
        float4 M = Wv[wbase + b * 4];
        // lane sub computes row `sub` of o and n
        float o_s = M.x * rox + M.y * roy + M.z * roz + M.w;  // origins homog = 1
        float n_s = M.x * rdx + M.y * rdy + M.z * rdz;        // dirs homog = 0
        // broadcast rows 0..2 across the quad (DPP quad_perm)
        float o0 = dpp_f<0x00>(o_s), o1 = dpp_f<0x55>(o_s), o2 = dpp_f<0xAA>(o_s);
        float n0 = dpp_f<0x00>(n_s), n1 = dpp_f<0x55>(n_s), n2 = dpp_f<0xAA>(n_s);

        // params for (b, g=sub); 4 distinct LDS addresses/wave, bank-disjoint
        int pi = (b * NG + sub) * 3;
        float4 p0 = P[pi + 0];
        float4 p1 = P[pi + 1];
        float4 p2 = P[pi + 2];
        float s00 = p0.x, s01 = p0.y, s02 = p0.z, s11 = p0.w;
        float s12 = p1.x, s22 = p1.y;
        float d0 = p1.z - o0, d1 = p1.w - o1, d2 = p2.x - o2;  // mu - o
        float c = p2.y;

        float v0 = s00 * n0 + s01 * n1 + s02 * n2;
        float v1 = s01 * n0 + s11 * n1 + s12 * n2;
        float v2 = s02 * n0 + s12 * n1 + s22 * n2;
        float nSn = v0 * n0 + v1 * n1 + v2 * n2;   // n^T S n
        float nSd = v0 * d0 + v1 * d1 + v2 * d2;   // n^T S (mu-o)
        float q0 = s00 * d0 + s01 * d1 + s02 * d2;
        float q1 = s01 * d0 + s11 * d1 + s12 * d2;
        float q2 = s02 * d0 + s12 * d1 + s22 * d2;
        float quad = q0 * d0 + q1 * d1 + q2 * d2;  // d^T S d

        float rn = frcp(nSn);                 // sigma_bar_sqr
        float mean = nSd * rn;                // mu_bar
        float expo = -0.5f * (quad - nSd * nSd * rn);
        float dens = c * __expf(expo);
        // w = sigmoid(100*mean - 1)
        float wsig = frcp(1.f + __expf(1.f - 100.f * mean));
        // arg = (10 - mean) / (sigma * sqrt(2)) = (10 - mean) * sqrt(nSn/2)
        float arg = (10.f - mean) * __builtin_amdgcn_sqrtf(nSn * 0.5f);
        // erf_poly (Abramowitz-Stegun 7.1.26)
        float sgn = arg > 0.f ? 1.f : -1.f;
        float xa = fabsf(arg);
        float t = frcp(1.f + 0.3275911f * xa);
        float poly = ((((1.061405429f * t - 1.453152027f) * t + 1.421413741f) * t
                       - 0.284496736f) * t + 0.254829592f) * t;
        float erf = sgn * (1.f - poly * __expf(-xa * xa));

        sum += dens * wsig * 0.5f * (1.f + erf);
    }

    // 4-lane butterfly reduction (DPP), then lane 0 of the quad writes
    sum += dpp_f<0xB1>(sum);  // quad_perm(1,0,3,2)
    sum += dpp_f<0x4E>(sum);  // quad_perm(2,3,0,1)
    if (sub == 0) out[ray] = __expf(-sum);
}

extern "C" void kernel_launch(void* const* d_in, const int* in_sizes, int n_in,
                              void* d_out, int out_size, void* d_ws, size_t ws_size,
                              hipStream_t stream) {
    const float* w2ls   = (const float*)d_in[0];
    const float* rays_o = (const float*)d_in[1];
    const float* rays_d = (const float*)d_in[2];
    const float* Gs     = (const float*)d_in[3];
    // d_in[4] = N_unique (unused by the math)
    float* out = (float*)d_out;

    const int R = in_sizes[1] / 3;
    const int threads = 256;
    const int blocks = (R * 4 + threads - 1) / threads;
    gauss_vis_kernel<<<blocks, threads, 0, stream>>>(w2ls, rays_o, rays_d, Gs, out, R);
}

// Round 2
// 27.520 us; speedup vs baseline: 1.0706x; 1.0706x over previous
//
#include <hip/hip_runtime.h>
#include <math.h>

// GaussianVisibility: R rays x B=24 bones x G=4 gaussians -> shadow map (R,)
// Memory-bound: w2ls (R,24,4,4) fp32 = 100.7 MB dominates. HBM roofline ~16.3us.
//
// R2 change vs R1 (29.5us): explicit software pipeline of the w2ls stream.
// Ping-pong register buffers of 6 bones (6 x float4 per lane) with loads for
// group t+1 issued before compute of group t -> per-wave in-flight bytes never
// drain to zero during compute (R1's unroll-4 pattern did). First 12 loads
// also issue before the LDS-param barrier. All buffer indexing is static
// (full unroll) to avoid scratch.
//
// Layout (unchanged): 4 lanes per ray; lane sub loads w2ls row `sub` (float4)
// and owns gaussian g=sub. o/n rows shared across the quad via DPP quad_perm.
// Per-(b,g) params (symmetric Sn1, mu, c) computed once per block into LDS.

#define NB 24
#define NG 4
#define BASE_SCALE 0.001f

template <int CTRL>
__device__ __forceinline__ float dpp_f(float x) {
    int r = __builtin_amdgcn_update_dpp(0, __float_as_int(x), CTRL, 0xF, 0xF, true);
    return __int_as_float(r);
}

__device__ __forceinline__ float frcp(float x) { return __builtin_amdgcn_rcpf(x); }

__global__ __launch_bounds__(256) void gauss_vis_kernel(
    const float* __restrict__ w2ls,
    const float* __restrict__ rays_o,
    const float* __restrict__ rays_d,
    const float* __restrict__ Gs,
    float* __restrict__ out,
    int R)
{
    __shared__ float4 P[NB * NG * 3];  // per (b,g): {s00,s01,s02,s11},{s12,s22,mu0,mu1},{mu2,c,-,-}

    const int tid = threadIdx.x;
    const int gid = blockIdx.x * 256 + tid;
    const int ray = gid >> 2;
    const int sub = tid & 3;
    const int rayc = ray < R ? ray : (R - 1);  // clamp for safe addresses

    const float4* __restrict__ Wv = (const float4*)w2ls;
    const size_t wbase = (size_t)rayc * (NB * 4) + sub;

    float4 A[6], Bf[6];
    // issue first 12 loads BEFORE the param barrier (independent of LDS)
#pragma unroll
    for (int k = 0; k < 6; ++k) A[k] = Wv[wbase + k * 4];
#pragma unroll
    for (int k = 0; k < 6; ++k) Bf[k] = Wv[wbase + (6 + k) * 4];

    const float rox = rays_o[rayc * 3 + 0];
    const float roy = rays_o[rayc * 3 + 1];
    const float roz = rays_o[rayc * 3 + 2];
    const float rdx = rays_d[rayc * 3 + 0];
    const float rdy = rays_d[rayc * 3 + 1];
    const float rdz = rays_d[rayc * 3 + 2];

    // ---- per-block param precompute (ray-independent) ----
    if (tid < NB * NG) {
        const float* gp = Gs + tid * 13;
        float mu0 = gp[0], mu1 = gp[1], mu2 = gp[2];
        float s0 = fabsf(gp[3]) + BASE_SCALE;
        float s1 = fabsf(gp[4]) + BASE_SCALE;
        float s2 = fabsf(gp[5]) + BASE_SCALE;
        float ax = gp[6], ay = gp[7], az = gp[8];
        float bx = gp[9], by = gp[10], bz = gp[11];
        float c = fabsf(gp[12]);
        float inv1 = 1.0f / sqrtf(ax * ax + ay * ay + az * az);
        float b1x = ax * inv1, b1y = ay * inv1, b1z = az * inv1;
        float dot = b1x * bx + b1y * by + b1z * bz;
        float t2x = bx - dot * b1x, t2y = by - dot * b1y, t2z = bz - dot * b1z;
        float inv2 = 1.0f / sqrtf(t2x * t2x + t2y * t2y + t2z * t2z);
        float b2x = t2x * inv2, b2y = t2y * inv2, b2z = t2z * inv2;
        float b3x = b1y * b2z - b1z * b2y;
        float b3y = b1z * b2x - b1x * b2z;
        float b3z = b1x * b2y - b1y * b2x;
        float w0 = 1.0f / (s0 * s0), w1 = 1.0f / (s1 * s1), w2 = 1.0f / (s2 * s2);
        float s00 = b1x * b1x * w0 + b1y * b1y * w1 + b1z * b1z * w2;
        float s01 = b1x * b2x * w0 + b1y * b2y * w1 + b1z * b2z * w2;
        float s02 = b1x * b3x * w0 + b1y * b3y * w1 + b1z * b3z * w2;
        float s11 = b2x * b2x * w0 + b2y * b2y * w1 + b2z * b2z * w2;
        float s12 = b2x * b3x * w0 + b2y * b3y * w1 + b2z * b3z * w2;
        float s22 = b3x * b3x * w0 + b3y * b3y * w1 + b3z * b3z * w2;
        P[tid * 3 + 0] = make_float4(s00, s01, s02, s11);
        P[tid * 3 + 1] = make_float4(s12, s22, mu0, mu1);
        P[tid * 3 + 2] = make_float4(mu2, c, 0.f, 0.f);
    }
    __syncthreads();

    // compute 6 bones from buffer `Mb`, base bone b0 (always inlined, static k)
    auto compute6 = [&](const float4 (&Mb)[6], int b0) -> float {
        float s = 0.f;
#pragma unroll
        for (int k = 0; k < 6; ++k) {
            const float4 M = Mb[k];
            float o_s = M.x * rox + M.y * roy + M.z * roz + M.w;
            float n_s = M.x * rdx + M.y * rdy + M.z * rdz;
            float o0 = dpp_f<0x00>(o_s), o1 = dpp_f<0x55>(o_s), o2 = dpp_f<0xAA>(o_s);
            float n0 = dpp_f<0x00>(n_s), n1 = dpp_f<0x55>(n_s), n2 = dpp_f<0xAA>(n_s);

            int pi = ((b0 + k) * NG + sub) * 3;
            float4 p0 = P[pi + 0];
            float4 p1 = P[pi + 1];
            float4 p2 = P[pi + 2];
            float s00 = p0.x, s01 = p0.y, s02 = p0.z, s11 = p0.w;
            float s12 = p1.x, s22 = p1.y;
            float d0 = p1.z - o0, d1 = p1.w - o1, d2 = p2.x - o2;
            float c = p2.y;

            float v0 = s00 * n0 + s01 * n1 + s02 * n2;
            float v1 = s01 * n0 + s11 * n1 + s12 * n2;
            float v2 = s02 * n0 + s12 * n1 + s22 * n2;
            float nSn = v0 * n0 + v1 * n1 + v2 * n2;
            float nSd = v0 * d0 + v1 * d1 + v2 * d2;
            float q0 = s00 * d0 + s01 * d1 + s02 * d2;
            float q1 = s01 * d0 + s11 * d1 + s12 * d2;
            float q2 = s02 * d0 + s12 * d1 + s22 * d2;
            float quad = q0 * d0 + q1 * d1 + q2 * d2;

            float rn = frcp(nSn);                 // sigma_bar_sqr
            float mean = nSd * rn;                // mu_bar
            float expo = -0.5f * (quad - nSd * nSd * rn);
            float dens = c * __expf(expo);
            float wsig = frcp(1.f + __expf(1.f - 100.f * mean));  // sigmoid(100*mean-1)
            float arg = (10.f - mean) * __builtin_amdgcn_sqrtf(nSn * 0.5f);
            float sgn = arg > 0.f ? 1.f : -1.f;
            float xa = fabsf(arg);
            float t = frcp(1.f + 0.3275911f * xa);
            float poly = ((((1.061405429f * t - 1.453152027f) * t + 1.421413741f) * t
                           - 0.284496736f) * t + 0.254829592f) * t;
            float erf = sgn * (1.f - poly * __expf(-xa * xa));

            s += dens * wsig * 0.5f * (1.f + erf);
        }
        return s;
    };

    // software pipeline: loads for group t+1 are in flight during compute of t
    float sum = compute6(A, 0);
#pragma unroll
    for (int k = 0; k < 6; ++k) A[k] = Wv[wbase + (12 + k) * 4];
    sum += compute6(Bf, 6);
#pragma unroll
    for (int k = 0; k < 6; ++k) Bf[k] = Wv[wbase + (18 + k) * 4];
    sum += compute6(A, 12);
    sum += compute6(Bf, 18);

    // 4-lane butterfly reduction (DPP), then lane 0 of the quad writes
    sum += dpp_f<0xB1>(sum);  // quad_perm(1,0,3,2)
    sum += dpp_f<0x4E>(sum);  // quad_perm(2,3,0,1)
    if (sub == 0 && ray < R) out[ray] = __expf(-sum);
}

extern "C" void kernel_launch(void* const* d_in, const int* in_sizes, int n_in,
                              void* d_out, int out_size, void* d_ws, size_t ws_size,
                              hipStream_t stream) {
    const float* w2ls   = (const float*)d_in[0];
    const float* rays_o = (const float*)d_in[1];
    const float* rays_d = (const float*)d_in[2];
    const float* Gs     = (const float*)d_in[3];
    float* out = (float*)d_out;

    const int R = in_sizes[1] / 3;
    const int threads = 256;
    const int blocks = (R * 4 + threads - 1) / threads;
    gauss_vis_kernel<<<blocks, threads, 0, stream>>>(w2ls, rays_o, rays_d, Gs, out, R);
}

// Round 4
// 26.800 us; speedup vs baseline: 1.0993x; 1.0268x over previous
//
#include <hip/hip_runtime.h>
#include <math.h>

// GaussianVisibility: R rays x B=24 bones x G=4 gaussians -> shadow map (R,)
// Memory-bound: w2ls (R,24,4,4) fp32 = 100.7 MB. HBM roofline ~16.3us.
//
// R4 change vs R2 (27.5us): 8 lanes per ray (was 4). Lane octet q=(half,sub):
// owns matrix row `sub`, gaussian g=sub, and the 12 bones of parity `half`.
//  - TLP: 2x waves (32/CU, 8/SIMD via __launch_bounds__(256,8)) -> ~2x loads
//    in flight per CU without relying on source-level pipelining the compiler
//    de-schedules (R2 lesson).
//  - Line efficiency: bones 2k,2k+1 are contiguous -> each wave load instr
//    covers 8 fully-consumed, 128B-aligned cache lines (was 16 half-lines).
// R3's global_load_lds staging NaN'd; reverted to proven direct loads.
//
// o/n rows shared across each quad via DPP quad_perm (VALU-only); halves
// merged with one __shfl_xor(4) at the end.
// Per-(b,g) params (symmetric Sn1, mu, c) computed once per block into LDS.

#define NB 24
#define NG 4
#define BASE_SCALE 0.001f

template <int CTRL>
__device__ __forceinline__ float dpp_f(float x) {
    int r = __builtin_amdgcn_update_dpp(0, __float_as_int(x), CTRL, 0xF, 0xF, true);
    return __int_as_float(r);
}

__device__ __forceinline__ float frcp(float x) { return __builtin_amdgcn_rcpf(x); }

__global__ __launch_bounds__(256, 8) void gauss_vis_kernel(
    const float* __restrict__ w2ls,
    const float* __restrict__ rays_o,
    const float* __restrict__ rays_d,
    const float* __restrict__ Gs,
    float* __restrict__ out,
    int R)
{
    __shared__ float4 P[NB * NG * 3];  // per (b,g): {s00,s01,s02,s11},{s12,s22,mu0,mu1},{mu2,c,-,-}

    const int tid = threadIdx.x;
    const int gid = blockIdx.x * 256 + tid;
    const int ray0 = gid >> 3;
    const int ray = ray0 < R ? ray0 : (R - 1);
    const int oct = tid & 7;   // lane within the ray-octet
    const int sub = oct & 3;   // matrix row + gaussian index
    const int half = oct >> 2; // bone parity

    // ---- per-block param precompute (ray-independent) ----
    if (tid < NB * NG) {
        const float* gp = Gs + tid * 13;
        float mu0 = gp[0], mu1 = gp[1], mu2 = gp[2];
        float s0 = fabsf(gp[3]) + BASE_SCALE;
        float s1 = fabsf(gp[4]) + BASE_SCALE;
        float s2 = fabsf(gp[5]) + BASE_SCALE;
        float ax = gp[6], ay = gp[7], az = gp[8];
        float bx = gp[9], by = gp[10], bz = gp[11];
        float c = fabsf(gp[12]);
        float inv1 = 1.0f / sqrtf(ax * ax + ay * ay + az * az);
        float b1x = ax * inv1, b1y = ay * inv1, b1z = az * inv1;
        float dot = b1x * bx + b1y * by + b1z * bz;
        float t2x = bx - dot * b1x, t2y = by - dot * b1y, t2z = bz - dot * b1z;
        float inv2 = 1.0f / sqrtf(t2x * t2x + t2y * t2y + t2z * t2z);
        float b2x = t2x * inv2, b2y = t2y * inv2, b2z = t2z * inv2;
        float b3x = b1y * b2z - b1z * b2y;
        float b3y = b1z * b2x - b1x * b2z;
        float b3z = b1x * b2y - b1y * b2x;
        float w0 = 1.0f / (s0 * s0), w1 = 1.0f / (s1 * s1), w2 = 1.0f / (s2 * s2);
        float s00 = b1x * b1x * w0 + b1y * b1y * w1 + b1z * b1z * w2;
        float s01 = b1x * b2x * w0 + b1y * b2y * w1 + b1z * b2z * w2;
        float s02 = b1x * b3x * w0 + b1y * b3y * w1 + b1z * b3z * w2;
        float s11 = b2x * b2x * w0 + b2y * b2y * w1 + b2z * b2z * w2;
        float s12 = b2x * b3x * w0 + b2y * b3y * w1 + b2z * b3z * w2;
        float s22 = b3x * b3x * w0 + b3y * b3y * w1 + b3z * b3z * w2;
        P[tid * 3 + 0] = make_float4(s00, s01, s02, s11);
        P[tid * 3 + 1] = make_float4(s12, s22, mu0, mu1);
        P[tid * 3 + 2] = make_float4(mu2, c, 0.f, 0.f);
    }
    __syncthreads();

    const float rox = rays_o[ray * 3 + 0];
    const float roy = rays_o[ray * 3 + 1];
    const float roz = rays_o[ray * 3 + 2];
    const float rdx = rays_d[ray * 3 + 0];
    const float rdy = rays_d[ray * 3 + 1];
    const float rdz = rays_d[ray * 3 + 2];

    // bone b = 2k + half lives at Wp[k*8] (float4 units); 128B/ray/step,
    // contiguous and 128B-aligned across the octet.
    const float4* __restrict__ Wp =
        (const float4*)w2ls + ((size_t)ray * (NB * 4) + half * 4 + sub);
    const int pi0 = (half * NG + sub) * 3;  // P index for bone `half`, +24 per k

    float sum = 0.f;
#pragma unroll 2
    for (int k = 0; k < 12; ++k) {
        const float4 M = Wp[k * 8];
        float o_s = M.x * rox + M.y * roy + M.z * roz + M.w;  // origins homog = 1
        float n_s = M.x * rdx + M.y * rdy + M.z * rdz;        // dirs homog = 0
        float o0 = dpp_f<0x00>(o_s), o1 = dpp_f<0x55>(o_s), o2 = dpp_f<0xAA>(o_s);
        float n0 = dpp_f<0x00>(n_s), n1 = dpp_f<0x55>(n_s), n2 = dpp_f<0xAA>(n_s);

        int pi = pi0 + k * 24;
        float4 p0 = P[pi + 0];
        float4 p1 = P[pi + 1];
        float4 p2 = P[pi + 2];
        float s00 = p0.x, s01 = p0.y, s02 = p0.z, s11 = p0.w;
        float s12 = p1.x, s22 = p1.y;
        float d0 = p1.z - o0, d1 = p1.w - o1, d2 = p2.x - o2;  // mu - o
        float c = p2.y;

        float v0 = s00 * n0 + s01 * n1 + s02 * n2;
        float v1 = s01 * n0 + s11 * n1 + s12 * n2;
        float v2 = s02 * n0 + s12 * n1 + s22 * n2;
        float nSn = v0 * n0 + v1 * n1 + v2 * n2;   // n^T S n
        float nSd = v0 * d0 + v1 * d1 + v2 * d2;   // n^T S (mu-o)
        float q0 = s00 * d0 + s01 * d1 + s02 * d2;
        float q1 = s01 * d0 + s11 * d1 + s12 * d2;
        float q2 = s02 * d0 + s12 * d1 + s22 * d2;
        float quad = q0 * d0 + q1 * d1 + q2 * d2;  // d^T S d

        float rn = frcp(nSn);                 // sigma_bar_sqr
        float mean = nSd * rn;                // mu_bar
        float expo = -0.5f * (quad - nSd * nSd * rn);
        float dens = c * __expf(expo);
        float wsig = frcp(1.f + __expf(1.f - 100.f * mean));  // sigmoid(100*mean-1)
        float arg = (10.f - mean) * __builtin_amdgcn_sqrtf(nSn * 0.5f);
        float sgn = arg > 0.f ? 1.f : -1.f;
        float xa = fabsf(arg);
        float t = frcp(1.f + 0.3275911f * xa);
        float poly = ((((1.061405429f * t - 1.453152027f) * t + 1.421413741f) * t
                       - 0.284496736f) * t + 0.254829592f) * t;
        float erf = sgn * (1.f - poly * __expf(-xa * xa));

        sum += dens * wsig * 0.5f * (1.f + erf);
    }

    // reduce: quad butterfly (DPP), then merge the two quads of the octet
    sum += dpp_f<0xB1>(sum);       // quad_perm(1,0,3,2)
    sum += dpp_f<0x4E>(sum);       // quad_perm(2,3,0,1)
    sum += __shfl_xor(sum, 4, 64); // half <-> half
    if (oct == 0 && ray0 < R) out[ray0] = __expf(-sum);
}

extern "C" void kernel_launch(void* const* d_in, const int* in_sizes, int n_in,
                              void* d_out, int out_size, void* d_ws, size_t ws_size,
                              hipStream_t stream) {
    const float* w2ls   = (const float*)d_in[0];
    const float* rays_o = (const float*)d_in[1];
    const float* rays_d = (const float*)d_in[2];
    const float* Gs     = (const float*)d_in[3];
    float* out = (float*)d_out;

    const int R = in_sizes[1] / 3;
    const int threads = 256;
    const long long total = (long long)R * 8;
    const int blocks = (int)((total + threads - 1) / threads);
    gauss_vis_kernel<<<blocks, threads, 0, stream>>>(w2ls, rays_o, rays_d, Gs, out, R);
}